// Round 14
// baseline (251.751 us; speedup 1.0000x reference)
//
#include <hip/hip_runtime.h>
#include <math.h>

#define HW 36864
#define CC 192

typedef __attribute__((ext_vector_type(4))) float f32x4;
typedef __attribute__((ext_vector_type(8))) short bf16x8;
typedef int i32x4a4 __attribute__((ext_vector_type(4), aligned(4)));

__device__ __forceinline__ float bf2f(unsigned short u) {
    return __uint_as_float(((unsigned int)u) << 16);
}
__device__ __forceinline__ unsigned short f2bf(float f) {
    unsigned int u = __float_as_uint(f);
    unsigned int r = (u + 0x7fffu + ((u >> 16) & 1u)) >> 16;
    return (unsigned short)r;
}

// ---------------------------------------------------------------------------
// Register-persistent-A column GEMM, section-pipelined (round-10 verified
// structure, 239.9 us session best). X is bf16 (pre-converted by cvt_x:
// fusion of the f32 convert was tried 3 ways — r1/r11 spill, r12 latency-
// exposed single-set — all lose to the split; direction closed).
// NT=6 for qkv: 1152 -> 576 blocks = single fully-resident scheduling
// round (no tail quantization), A-fragments amortized over 6 tiles.
// SWAP=true compute transposes D placement (HW-verified r7); bf16 store via
// LDS-transpose epilogue (r10-verified: WRITE == 84.9 MB ideal); f32 store
// direct float4.
// (r13 resubmit: NT=6 delta audited in-bounds; container death matches the
// r4/r8 infra-flake signature, both of which passed byte-identical resubmits.)
// ---------------------------------------------------------------------------
template<bool OUTBF, bool SWAP, int NT, int NZ>
__global__ __launch_bounds__(256, 3) void gemm_rpa(
    const unsigned short* __restrict__ A,
    const unsigned short* __restrict__ X,
    void* __restrict__ Outv,
    long aBatchStride, long xBatchStride, long oBatchStride)
{
    const int nx = gridDim.x;
    int bx = blockIdx.x;
    if ((nx & 7) == 0) {                       // XCD chunk swizzle (bijective)
        const int cpx = nx >> 3;
        bx = (bx & 7) * cpx + (bx >> 3);
    }
    const int z  = (NZ > 1) ? (bx % NZ) : 0;
    const int ng = (NZ > 1) ? (bx / NZ) : bx;
    const int b  = blockIdx.y;
    const int mbase = z * 192;
    const int n00 = ng * (NT * 64);

    const int tid = threadIdx.x;
    const int lane = tid & 63;
    const int wave = tid >> 6;
    const int ml = lane & 15, qk = lane >> 4;
    const int kp = tid & 31;   // k-pair within 64-k section
    const int nc = tid >> 5;   // n-chunk of 8 (0..7)

    // stride 202 shorts = 101 dwords (101 % 32 == 5): <=2-way conflicts
    __shared__ __attribute__((aligned(16))) unsigned short Xs[64 * 202];
    // per-wave epilogue transpose slice: 16 rows x 64 cols, stride 72 shorts
    __shared__ __attribute__((aligned(16))) unsigned short Es[4][16][72];

    // ---- A fragments: 48 rows x 192 k per wave, loaded once per block ----
    const unsigned short* Ab = A + (long)b * aBatchStride;
    bf16x8 afr[3][6];
#pragma unroll
    for (int f = 0; f < 3; ++f) {
        const unsigned short* row = Ab + (long)(mbase + wave * 48 + f * 16 + ml) * 192 + qk * 8;
#pragma unroll
        for (int kk = 0; kk < 6; ++kk)
            afr[f][kk] = *(const bf16x8*)(row + kk * 32);
    }

    const unsigned short* Xg = X + (long)b * xBatchStride + n00 + nc * 8;

    f32x4 acc[3][4];  // [m-frag][n-subtile], carried across k-sections
#pragma unroll
    for (int f = 0; f < 3; ++f)
#pragma unroll
        for (int s = 0; s < 4; ++s)
            acc[f][s] = (f32x4){0.f, 0.f, 0.f, 0.f};

    auto LOAD = [&](int g, int4* r) {
        const int t = g / 3, sec = g - 3 * t;
        const unsigned short* p = Xg + (long)(sec * 64 + 2 * kp) * HW + t * 64;
        r[0] = *(const int4*)(p);
        r[1] = *(const int4*)(p + HW);
    };
    auto WRITE = [&](int g, const int4* r) {
        const int t = g / 3, sec = g - 3 * t;
        const int k = sec * 64 + 2 * kp;
        const unsigned short* u0 = (const unsigned short*)&r[0];
        const unsigned short* u1 = (const unsigned short*)&r[1];
#pragma unroll
        for (int j = 0; j < 8; ++j)
            *(unsigned int*)&Xs[(nc * 8 + j) * 202 + k] =
                (unsigned int)u0[j] | ((unsigned int)u1[j] << 16);
    };
    auto COMPUTE = [&](int g) {
        const int sec = g % 3;
#pragma unroll
        for (int s = 0; s < 4; ++s) {
#pragma unroll
            for (int kl = 0; kl < 2; ++kl) {
                bf16x8 bfr;
                {
                    const unsigned short* p = &Xs[(s * 16 + ml) * 202 + sec * 64 + kl * 32 + qk * 8];
                    union { bf16x8 v; unsigned int u[4]; } tmp;
                    tmp.u[0] = *(const unsigned int*)(p + 0);
                    tmp.u[1] = *(const unsigned int*)(p + 2);
                    tmp.u[2] = *(const unsigned int*)(p + 4);
                    tmp.u[3] = *(const unsigned int*)(p + 6);
                    bfr = tmp.v;
                }
#pragma unroll
                for (int f = 0; f < 3; ++f) {
                    if (SWAP)
                        acc[f][s] = __builtin_amdgcn_mfma_f32_16x16x32_bf16(bfr, afr[f][sec * 2 + kl], acc[f][s], 0, 0, 0);
                    else
                        acc[f][s] = __builtin_amdgcn_mfma_f32_16x16x32_bf16(afr[f][sec * 2 + kl], bfr, acc[f][s], 0, 0, 0);
                }
            }
        }
    };
    auto STORE = [&](int t) {
        const int n0 = n00 + t * 64;
#pragma unroll
        for (int f = 0; f < 3; ++f) {
            if (SWAP) {
                if (OUTBF) {
                    // ---- LDS-transpose epilogue (wave-local, no barrier) ----
#pragma unroll
                    for (int s = 0; s < 4; ++s) {
                        unsigned int* wp = (unsigned int*)&Es[wave][ml][s * 16 + qk * 4];
                        wp[0] = (unsigned int)f2bf(acc[f][s][0]) | ((unsigned int)f2bf(acc[f][s][1]) << 16);
                        wp[1] = (unsigned int)f2bf(acc[f][s][2]) | ((unsigned int)f2bf(acc[f][s][3]) << 16);
                        acc[f][s] = (f32x4){0.f, 0.f, 0.f, 0.f};
                    }
#pragma unroll
                    for (int p = 0; p < 2; ++p) {
                        const int r  = p * 8 + (lane >> 3);
                        const int cb = (lane & 7) * 8;
                        int4 v = *(const int4*)&Es[wave][r][cb];
                        const int gm = mbase + wave * 48 + f * 16 + r;
                        const int gn = n0 + cb;
                        *(int4*)((unsigned short*)Outv + (long)b * oBatchStride + (long)gm * HW + gn) = v;
                    }
                } else {
                    const int gm = mbase + wave * 48 + f * 16 + ml;
#pragma unroll
                    for (int s = 0; s < 4; ++s) {
                        const int gn = n0 + s * 16 + qk * 4;
                        float4 v;
                        v.x = acc[f][s][0]; v.y = acc[f][s][1];
                        v.z = acc[f][s][2]; v.w = acc[f][s][3];
                        *(float4*)((float*)Outv + (long)b * oBatchStride + (long)gm * HW + gn) = v;
                        acc[f][s] = (f32x4){0.f, 0.f, 0.f, 0.f};
                    }
                }
            } else {
#pragma unroll
                for (int s = 0; s < 4; ++s) {
                    const int gm = mbase + wave * 48 + f * 16 + qk * 4;
                    const int gn = n0 + s * 16 + ml;
#pragma unroll
                    for (int i = 0; i < 4; ++i) {
                        if (OUTBF)
                            ((unsigned short*)Outv)[(long)b * oBatchStride + (long)(gm + i) * HW + gn] = f2bf(acc[f][s][i]);
                        else
                            ((float*)Outv)[(long)b * oBatchStride + (long)(gm + i) * HW + gn] = acc[f][s][i];
                    }
                    acc[f][s] = (f32x4){0.f, 0.f, 0.f, 0.f};
                }
            }
        }
    };

    constexpr int NS = NT * 3;
    int4 sA[2], sB[2];   // two in-flight staging sets (8 VGPRs each)

    // prologue
    LOAD(0, sA);
    WRITE(0, sA);
    LOAD(1, sB);
    __syncthreads();

#pragma unroll
    for (int g = 0; g < NS; ++g) {
        if ((g & 1) == 0) {
            if (g + 2 < NS) LOAD(g + 2, sA);
            COMPUTE(g);
            if (g + 1 < NS) WRITE(g + 1, sB);
        } else {
            if (g + 2 < NS) LOAD(g + 2, sB);
            COMPUTE(g);
            if (g + 1 < NS) WRITE(g + 1, sA);
        }
        if (g % 3 == 2) STORE(g / 3);
        if (g + 1 < NS) __syncthreads();
    }
}

// ---------------------------------------------------------------------------
// Depthwise 3x3 conv (SAME, zero pad), full lane utilization + vertical
// rolling reuse (verified round 6: dropped out of top-5).
// ---------------------------------------------------------------------------
__global__ __launch_bounds__(256) void dwconv_kernel(
    const unsigned short* __restrict__ qkv,
    const float* __restrict__ wdw,
    unsigned short* __restrict__ dwout,
    float* __restrict__ ssq)
{
    const int rt = blockIdx.x;   // 0..3 (48-row tiles)
    const int ch = blockIdx.y;   // 0..575
    const int b  = blockIdx.z;
    const int tid = threadIdx.x;
    const int lane = tid & 63;
    const int t  = tid & 31;     // px-strip lane, 6 px each (all active)
    const int rowgrp = tid >> 5; // 0..7, 6 output rows each
    const int gh = rt * 48 + rowgrp * 6;

    const float* wp = wdw + ch * 9;
    const float w00 = wp[0], w01 = wp[1], w02 = wp[2];
    const float w10 = wp[3], w11 = wp[4], w12 = wp[5];
    const float w20 = wp[6], w21 = wp[7], w22 = wp[8];

    const long chbase = (long)(b * 576 + ch) * HW;
    const unsigned short* src = qkv + chbase + t * 6;
    unsigned short* dst = dwout + chbase + t * 6;

    float rbuf[3][7];
    float lf[3];

    auto LOADROW = [&](int hr, int sl) {
        if (hr >= 0 && hr < 192) {
            i32x4a4 v = *(const i32x4a4*)(src + (long)hr * 192);
            const unsigned short* u = (const unsigned short*)&v;
#pragma unroll
            for (int j = 0; j < 7; ++j) rbuf[sl][j] = bf2f(u[j]);
            if (t == 31) rbuf[sl][6] = 0.f;   // px 192 = out of image
        } else {
#pragma unroll
            for (int j = 0; j < 7; ++j) rbuf[sl][j] = 0.f;
        }
        float l = __shfl(rbuf[sl][5], lane - 1, 64);
        lf[sl] = (t == 0) ? 0.f : l;
    };

    LOADROW(gh - 1, 0);
    LOADROW(gh,     1);

    float myssq = 0.f;

#pragma unroll
    for (int r = 0; r < 6; ++r) {
        const int sla = r % 3;          // row above (gh+r-1)
        const int slc = (r + 1) % 3;    // center    (gh+r)
        const int slb = (r + 2) % 3;    // below     (gh+r+1)
        LOADROW(gh + r + 1, slb);

        float o[6];
#pragma unroll
        for (int j = 0; j < 6; ++j) {
            const float a0 = (j == 0) ? lf[sla] : rbuf[sla][j - 1];
            const float b0 = (j == 0) ? lf[slc] : rbuf[slc][j - 1];
            const float c0 = (j == 0) ? lf[slb] : rbuf[slb][j - 1];
            o[j] = w00 * a0 + w01 * rbuf[sla][j] + w02 * rbuf[sla][j + 1]
                 + w10 * b0 + w11 * rbuf[slc][j] + w12 * rbuf[slc][j + 1]
                 + w20 * c0 + w21 * rbuf[slb][j] + w22 * rbuf[slb][j + 1];
        }

        unsigned int* dp = (unsigned int*)(dst + (long)(gh + r) * 192);
        dp[0] = (unsigned int)f2bf(o[0]) | ((unsigned int)f2bf(o[1]) << 16);
        dp[1] = (unsigned int)f2bf(o[2]) | ((unsigned int)f2bf(o[3]) << 16);
        dp[2] = (unsigned int)f2bf(o[4]) | ((unsigned int)f2bf(o[5]) << 16);

#pragma unroll
        for (int j = 0; j < 6; ++j) myssq += o[j] * o[j];
    }

    if (ch < 384) {
#pragma unroll
        for (int off = 32; off > 0; off >>= 1) myssq += __shfl_xor(myssq, off, 64);
        __shared__ float red[4];
        if (lane == 0) red[tid >> 6] = myssq;
        __syncthreads();
        if (tid == 0) atomicAdd(&ssq[b * 384 + ch], red[0] + red[1] + red[2] + red[3]);
    }
}

// ---------------------------------------------------------------------------
// Gram: gram[b,h,d,e] += sum_n q[d][n]*k[e][n]. 4 waves per block, each wave
// a 128-col sub-chunk of a 512-col chunk; LDS-reduce across waves, then one
// set of atomics per block.
// ---------------------------------------------------------------------------
__global__ __launch_bounds__(256) void gram_kernel(
    const unsigned short* __restrict__ dwb, float* __restrict__ gram)
{
    const int chunk = blockIdx.x;  // 0..71 (512-col chunks)
    const int bh = blockIdx.y;     // 0..7
    const int b = bh >> 2, h = bh & 3;
    const int tid = threadIdx.x;
    const int wave = tid >> 6;
    const int lane = tid & 63;
    const int row = lane & 15, qk = lane >> 4;
    const long n0 = (long)chunk * 512 + wave * 128;

    const unsigned short* qb = dwb + (long)(b * 576 + h * 48) * HW + n0;
    const unsigned short* kb = dwb + (long)(b * 576 + 192 + h * 48) * HW + n0;

    f32x4 acc[3][3];
#pragma unroll
    for (int f = 0; f < 3; ++f)
#pragma unroll
        for (int g = 0; g < 3; ++g) acc[f][g] = (f32x4){0.f, 0.f, 0.f, 0.f};

#pragma unroll
    for (int kk = 0; kk < 128; kk += 32) {
        const int col = kk + qk * 8;
        bf16x8 aq[3], bk[3];
#pragma unroll
        for (int f = 0; f < 3; ++f) aq[f] = *(const bf16x8*)(qb + (long)(f * 16 + row) * HW + col);
#pragma unroll
        for (int g = 0; g < 3; ++g) bk[g] = *(const bf16x8*)(kb + (long)(g * 16 + row) * HW + col);
#pragma unroll
        for (int f = 0; f < 3; ++f)
#pragma unroll
            for (int g = 0; g < 3; ++g)
                acc[f][g] = __builtin_amdgcn_mfma_f32_16x16x32_bf16(aq[f], bk[g], acc[f][g], 0, 0, 0);
    }

    // cross-wave LDS reduction (padded stride 37: conflict-light)
    __shared__ float sg[4][64][37];
#pragma unroll
    for (int f = 0; f < 3; ++f)
#pragma unroll
        for (int g = 0; g < 3; ++g)
#pragma unroll
            for (int i = 0; i < 4; ++i)
                sg[wave][lane][f * 12 + g * 4 + i] = acc[f][g][i];
    __syncthreads();

    const int rl = tid >> 2;
    const int i0 = (tid & 3) * 9;
    const int rrow = rl & 15, rqk = rl >> 4;
    float* gb = gram + bh * 2304;
#pragma unroll
    for (int j = 0; j < 9; ++j) {
        const int idx = i0 + j;
        const float v = sg[0][rl][idx] + sg[1][rl][idx] + sg[2][rl][idx] + sg[3][rl][idx];
        const int f = idx / 12, rem = idx - f * 12, g = rem >> 2, i = rem & 3;
        atomicAdd(&gb[(f * 16 + rqk * 4 + i) * 48 + g * 16 + rrow], v);
    }
}

// ---------------------------------------------------------------------------
// attn = softmax( gram / (|q_d||k_e|) * softplus(logT) + eps ) over e
// ---------------------------------------------------------------------------
__global__ __launch_bounds__(64) void attn_kernel(
    const float* __restrict__ gram, const float* __restrict__ ssq,
    const float* __restrict__ lt, float* __restrict__ attn)
{
    const int bh = blockIdx.x;
    const int b = bh >> 2, h = bh & 3;
    const int d = threadIdx.x;
    if (d >= 48) return;
    const float temp = log1pf(expf(lt[h])) + 1e-6f;
    const float invq = 1.f / fmaxf(sqrtf(ssq[b * 384 + h * 48 + d]), 1e-12f);
    float p[48];
    float mx = -1e30f;
#pragma unroll
    for (int e = 0; e < 48; ++e) {
        float invk = 1.f / fmaxf(sqrtf(ssq[b * 384 + 192 + h * 48 + e]), 1e-12f);
        float g = gram[bh * 2304 + d * 48 + e] * invq * invk * temp;
        p[e] = g;
        mx = fmaxf(mx, g);
    }
    float sum = 0.f;
#pragma unroll
    for (int e = 0; e < 48; ++e) { float x = expf(p[e] - mx); p[e] = x; sum += x; }
    const float inv = 1.f / sum;
#pragma unroll
    for (int e = 0; e < 48; ++e) attn[bh * 2304 + d * 48 + e] = p[e] * inv;
}

// ---------------------------------------------------------------------------
// M[b][o][h*48+e] = sum_d wproj[o][h*48+d] * attn[b][h][d][e]   (bf16 out)
// ---------------------------------------------------------------------------
__global__ __launch_bounds__(192) void mproj_kernel(
    const float* __restrict__ wproj, const float* __restrict__ attn,
    unsigned short* __restrict__ Mb)
{
    const int o = blockIdx.x;
    const int b = blockIdx.y;
    const int he = threadIdx.x;
    const int h = he / 48, e = he - h * 48;
    const float* ar = attn + ((b * 4 + h) * 48) * 48 + e;
    const float* wr = wproj + o * 192 + h * 48;
    float acc = 0.f;
#pragma unroll
    for (int d = 0; d < 48; ++d) acc += wr[d] * ar[d * 48];
    Mb[(long)(b * 192 + o) * 192 + he] = f2bf(acc);
}

__global__ void cvt_bf16_kernel(const float* __restrict__ in,
                                unsigned short* __restrict__ out, int n)
{
    int i = blockIdx.x * 256 + threadIdx.x;
    if (i < n) out[i] = f2bf(in[i]);
}

// X f32 -> bf16, 8 elems/thread, exact grid (no bounds check needed)
__global__ __launch_bounds__(256) void cvt_x_kernel(
    const float* __restrict__ in, unsigned short* __restrict__ out)
{
    const long i = ((long)blockIdx.x * 256 + threadIdx.x) * 8;
    float4 a = *(const float4*)(in + i);
    float4 b = *(const float4*)(in + i + 4);
    int4 st;
    unsigned short* u = (unsigned short*)&st;
    u[0] = f2bf(a.x); u[1] = f2bf(a.y); u[2] = f2bf(a.z); u[3] = f2bf(a.w);
    u[4] = f2bf(b.x); u[5] = f2bf(b.y); u[6] = f2bf(b.z); u[7] = f2bf(b.w);
    *(int4*)(out + i) = st;
}

// ---------------------------------------------------------------------------
extern "C" void kernel_launch(void* const* d_in, const int* in_sizes, int n_in,
                              void* d_out, int out_size, void* d_ws, size_t ws_size,
                              hipStream_t stream)
{
    const float* x      = (const float*)d_in[0];
    const float* w_qkv  = (const float*)d_in[1];
    const float* w_dw   = (const float*)d_in[2];
    const float* w_proj = (const float*)d_in[3];
    const float* lt     = (const float*)d_in[4];

    char* ws = (char*)d_ws;
    unsigned short* wqkv_b = (unsigned short*)(ws + 0);          // 221184 B
    float* gram            = (float*)(ws + 221184);              // 73728 B
    float* ssq             = (float*)(ws + 294912);              // 3072 B
    float* attn            = (float*)(ws + 297984);              // 73728 B
    unsigned short* Mb     = (unsigned short*)(ws + 371712);     // 147456 B
    unsigned short* qkvb   = (unsigned short*)(ws + 524288);     // 84934656 B
    unsigned short* dwb    = (unsigned short*)(ws + 524288 + 84934656ll);
    // xbf ALIASES dwb: xbf is only live before the qkv GEMM completes;
    // dwb is first written by dwconv (after it). Proven r5-r10.
    unsigned short* xbf    = dwb;                                // 28311552 B

    // zero the atomic accumulators (gram + ssq are adjacent)
    hipMemsetAsync(gram, 0, 73728 + 3072, stream);

    // w_qkv -> bf16
    cvt_bf16_kernel<<<dim3((110592 + 255) / 256), 256, 0, stream>>>(w_qkv, wqkv_b, 110592);

    // x -> bf16 (2*192*36864 = 14155776 elems, 8/thread -> 6912 blocks exact)
    cvt_x_kernel<<<dim3(6912), 256, 0, stream>>>(x, xbf);

    // qkv = w_qkv @ x  (M=576, K=192, N=HW per batch)
    // NT=6: grid (576/6)*3 = 288 (div by 8); 576 total blocks = one fully
    // resident scheduling round (was 1152 -> ~50%-fill second round).
    gemm_rpa<true, true, 6, 3><<<dim3(288, 2), 256, 0, stream>>>(
        wqkv_b, xbf, (void*)qkvb,
        0L, (long)192 * HW, (long)576 * HW);

    // depthwise 3x3 + sumsq(q,k)  (overwrites the xbf alias region)
    dwconv_kernel<<<dim3(4, 576, 2), 256, 0, stream>>>(qkvb, w_dw, dwb, ssq);

    // gram = q @ k^T per (b, head): 4-wave blocks, LDS-reduced
    gram_kernel<<<dim3(72, 8), 256, 0, stream>>>(dwb, gram);

    // softmax(normalized gram * temperature)
    attn_kernel<<<dim3(8), 64, 0, stream>>>(gram, ssq, lt, attn);

    // M = w_proj @ attn (per batch, per head), bf16
    mproj_kernel<<<dim3(192, 2), 192, 0, stream>>>(w_proj, attn, Mb);

    // out = M @ v  (M=192, K=192, N=HW per batch), fp32 out
    gemm_rpa<false, true, 2, 1><<<dim3(288, 2), 256, 0, stream>>>(
        Mb, dwb + (long)384 * HW, d_out,
        (long)192 * 192, (long)576 * HW, (long)192 * HW);
}

// Round 15
// 238.394 us; speedup vs baseline: 1.0560x; 1.0560x over previous
//
#include <hip/hip_runtime.h>
#include <math.h>

#define HW 36864
#define CC 192

typedef __attribute__((ext_vector_type(4))) float f32x4;
typedef __attribute__((ext_vector_type(8))) short bf16x8;
typedef int i32x4a4 __attribute__((ext_vector_type(4), aligned(4)));

__device__ __forceinline__ float bf2f(unsigned short u) {
    return __uint_as_float(((unsigned int)u) << 16);
}
__device__ __forceinline__ unsigned short f2bf(float f) {
    unsigned int u = __float_as_uint(f);
    unsigned int r = (u + 0x7fffu + ((u >> 16) & 1u)) >> 16;
    return (unsigned short)r;
}

// ---------------------------------------------------------------------------
// Register-persistent-A column GEMM, section-pipelined (round-10 verified
// structure, 239.9 us session best).
// NT sizing law (measured r10 vs r14): blocks/CU fill dominates. NT=3 qkv
// (1152 blk = 4.5/CU: one full 3/CU round + tail) = 46.3 us; NT=6 (576 blk
// = 2.25/CU, permanently under-filled) = 56.1 us. Finer NT > coarser.
// This round: out-gemm NT 2 -> 1 (576 -> 1152 blocks) for the same reason;
// its A (Mb, 147 KB) is L2-hot so re-read cost is nil.
// SWAP=true compute transposes D placement (HW-verified r7); bf16 store via
// LDS-transpose epilogue (r10-verified: WRITE == 84.9 MB ideal); f32 store
// direct float4. X pre-converted bf16 (fusion closed: r1/r11 spill, r12
// latency-exposed).
// ---------------------------------------------------------------------------
template<bool OUTBF, bool SWAP, int NT, int NZ>
__global__ __launch_bounds__(256, 3) void gemm_rpa(
    const unsigned short* __restrict__ A,
    const unsigned short* __restrict__ X,
    void* __restrict__ Outv,
    long aBatchStride, long xBatchStride, long oBatchStride)
{
    const int nx = gridDim.x;
    int bx = blockIdx.x;
    if ((nx & 7) == 0) {                       // XCD chunk swizzle (bijective)
        const int cpx = nx >> 3;
        bx = (bx & 7) * cpx + (bx >> 3);
    }
    const int z  = (NZ > 1) ? (bx % NZ) : 0;
    const int ng = (NZ > 1) ? (bx / NZ) : bx;
    const int b  = blockIdx.y;
    const int mbase = z * 192;
    const int n00 = ng * (NT * 64);

    const int tid = threadIdx.x;
    const int lane = tid & 63;
    const int wave = tid >> 6;
    const int ml = lane & 15, qk = lane >> 4;
    const int kp = tid & 31;   // k-pair within 64-k section
    const int nc = tid >> 5;   // n-chunk of 8 (0..7)

    // stride 202 shorts = 101 dwords (101 % 32 == 5): <=2-way conflicts
    __shared__ __attribute__((aligned(16))) unsigned short Xs[64 * 202];
    // per-wave epilogue transpose slice: 16 rows x 64 cols, stride 72 shorts
    __shared__ __attribute__((aligned(16))) unsigned short Es[4][16][72];

    // ---- A fragments: 48 rows x 192 k per wave, loaded once per block ----
    const unsigned short* Ab = A + (long)b * aBatchStride;
    bf16x8 afr[3][6];
#pragma unroll
    for (int f = 0; f < 3; ++f) {
        const unsigned short* row = Ab + (long)(mbase + wave * 48 + f * 16 + ml) * 192 + qk * 8;
#pragma unroll
        for (int kk = 0; kk < 6; ++kk)
            afr[f][kk] = *(const bf16x8*)(row + kk * 32);
    }

    const unsigned short* Xg = X + (long)b * xBatchStride + n00 + nc * 8;

    f32x4 acc[3][4];  // [m-frag][n-subtile], carried across k-sections
#pragma unroll
    for (int f = 0; f < 3; ++f)
#pragma unroll
        for (int s = 0; s < 4; ++s)
            acc[f][s] = (f32x4){0.f, 0.f, 0.f, 0.f};

    auto LOAD = [&](int g, int4* r) {
        const int t = g / 3, sec = g - 3 * t;
        const unsigned short* p = Xg + (long)(sec * 64 + 2 * kp) * HW + t * 64;
        r[0] = *(const int4*)(p);
        r[1] = *(const int4*)(p + HW);
    };
    auto WRITE = [&](int g, const int4* r) {
        const int t = g / 3, sec = g - 3 * t;
        const int k = sec * 64 + 2 * kp;
        const unsigned short* u0 = (const unsigned short*)&r[0];
        const unsigned short* u1 = (const unsigned short*)&r[1];
#pragma unroll
        for (int j = 0; j < 8; ++j)
            *(unsigned int*)&Xs[(nc * 8 + j) * 202 + k] =
                (unsigned int)u0[j] | ((unsigned int)u1[j] << 16);
    };
    auto COMPUTE = [&](int g) {
        const int sec = g % 3;
#pragma unroll
        for (int s = 0; s < 4; ++s) {
#pragma unroll
            for (int kl = 0; kl < 2; ++kl) {
                bf16x8 bfr;
                {
                    const unsigned short* p = &Xs[(s * 16 + ml) * 202 + sec * 64 + kl * 32 + qk * 8];
                    union { bf16x8 v; unsigned int u[4]; } tmp;
                    tmp.u[0] = *(const unsigned int*)(p + 0);
                    tmp.u[1] = *(const unsigned int*)(p + 2);
                    tmp.u[2] = *(const unsigned int*)(p + 4);
                    tmp.u[3] = *(const unsigned int*)(p + 6);
                    bfr = tmp.v;
                }
#pragma unroll
                for (int f = 0; f < 3; ++f) {
                    if (SWAP)
                        acc[f][s] = __builtin_amdgcn_mfma_f32_16x16x32_bf16(bfr, afr[f][sec * 2 + kl], acc[f][s], 0, 0, 0);
                    else
                        acc[f][s] = __builtin_amdgcn_mfma_f32_16x16x32_bf16(afr[f][sec * 2 + kl], bfr, acc[f][s], 0, 0, 0);
                }
            }
        }
    };
    auto STORE = [&](int t) {
        const int n0 = n00 + t * 64;
#pragma unroll
        for (int f = 0; f < 3; ++f) {
            if (SWAP) {
                if (OUTBF) {
                    // ---- LDS-transpose epilogue (wave-local, no barrier) ----
#pragma unroll
                    for (int s = 0; s < 4; ++s) {
                        unsigned int* wp = (unsigned int*)&Es[wave][ml][s * 16 + qk * 4];
                        wp[0] = (unsigned int)f2bf(acc[f][s][0]) | ((unsigned int)f2bf(acc[f][s][1]) << 16);
                        wp[1] = (unsigned int)f2bf(acc[f][s][2]) | ((unsigned int)f2bf(acc[f][s][3]) << 16);
                        acc[f][s] = (f32x4){0.f, 0.f, 0.f, 0.f};
                    }
#pragma unroll
                    for (int p = 0; p < 2; ++p) {
                        const int r  = p * 8 + (lane >> 3);
                        const int cb = (lane & 7) * 8;
                        int4 v = *(const int4*)&Es[wave][r][cb];
                        const int gm = mbase + wave * 48 + f * 16 + r;
                        const int gn = n0 + cb;
                        *(int4*)((unsigned short*)Outv + (long)b * oBatchStride + (long)gm * HW + gn) = v;
                    }
                } else {
                    const int gm = mbase + wave * 48 + f * 16 + ml;
#pragma unroll
                    for (int s = 0; s < 4; ++s) {
                        const int gn = n0 + s * 16 + qk * 4;
                        float4 v;
                        v.x = acc[f][s][0]; v.y = acc[f][s][1];
                        v.z = acc[f][s][2]; v.w = acc[f][s][3];
                        *(float4*)((float*)Outv + (long)b * oBatchStride + (long)gm * HW + gn) = v;
                        acc[f][s] = (f32x4){0.f, 0.f, 0.f, 0.f};
                    }
                }
            } else {
#pragma unroll
                for (int s = 0; s < 4; ++s) {
                    const int gm = mbase + wave * 48 + f * 16 + qk * 4;
                    const int gn = n0 + s * 16 + ml;
#pragma unroll
                    for (int i = 0; i < 4; ++i) {
                        if (OUTBF)
                            ((unsigned short*)Outv)[(long)b * oBatchStride + (long)(gm + i) * HW + gn] = f2bf(acc[f][s][i]);
                        else
                            ((float*)Outv)[(long)b * oBatchStride + (long)(gm + i) * HW + gn] = acc[f][s][i];
                    }
                    acc[f][s] = (f32x4){0.f, 0.f, 0.f, 0.f};
                }
            }
        }
    };

    constexpr int NS = NT * 3;
    int4 sA[2], sB[2];   // two in-flight staging sets (8 VGPRs each)

    // prologue
    LOAD(0, sA);
    WRITE(0, sA);
    LOAD(1, sB);
    __syncthreads();

#pragma unroll
    for (int g = 0; g < NS; ++g) {
        if ((g & 1) == 0) {
            if (g + 2 < NS) LOAD(g + 2, sA);
            COMPUTE(g);
            if (g + 1 < NS) WRITE(g + 1, sB);
        } else {
            if (g + 2 < NS) LOAD(g + 2, sB);
            COMPUTE(g);
            if (g + 1 < NS) WRITE(g + 1, sA);
        }
        if (g % 3 == 2) STORE(g / 3);
        if (g + 1 < NS) __syncthreads();
    }
}

// ---------------------------------------------------------------------------
// Depthwise 3x3 conv (SAME, zero pad), full lane utilization + vertical
// rolling reuse (verified round 6: dropped out of top-5).
// ---------------------------------------------------------------------------
__global__ __launch_bounds__(256) void dwconv_kernel(
    const unsigned short* __restrict__ qkv,
    const float* __restrict__ wdw,
    unsigned short* __restrict__ dwout,
    float* __restrict__ ssq)
{
    const int rt = blockIdx.x;   // 0..3 (48-row tiles)
    const int ch = blockIdx.y;   // 0..575
    const int b  = blockIdx.z;
    const int tid = threadIdx.x;
    const int lane = tid & 63;
    const int t  = tid & 31;     // px-strip lane, 6 px each (all active)
    const int rowgrp = tid >> 5; // 0..7, 6 output rows each
    const int gh = rt * 48 + rowgrp * 6;

    const float* wp = wdw + ch * 9;
    const float w00 = wp[0], w01 = wp[1], w02 = wp[2];
    const float w10 = wp[3], w11 = wp[4], w12 = wp[5];
    const float w20 = wp[6], w21 = wp[7], w22 = wp[8];

    const long chbase = (long)(b * 576 + ch) * HW;
    const unsigned short* src = qkv + chbase + t * 6;
    unsigned short* dst = dwout + chbase + t * 6;

    float rbuf[3][7];
    float lf[3];

    auto LOADROW = [&](int hr, int sl) {
        if (hr >= 0 && hr < 192) {
            i32x4a4 v = *(const i32x4a4*)(src + (long)hr * 192);
            const unsigned short* u = (const unsigned short*)&v;
#pragma unroll
            for (int j = 0; j < 7; ++j) rbuf[sl][j] = bf2f(u[j]);
            if (t == 31) rbuf[sl][6] = 0.f;   // px 192 = out of image
        } else {
#pragma unroll
            for (int j = 0; j < 7; ++j) rbuf[sl][j] = 0.f;
        }
        float l = __shfl(rbuf[sl][5], lane - 1, 64);
        lf[sl] = (t == 0) ? 0.f : l;
    };

    LOADROW(gh - 1, 0);
    LOADROW(gh,     1);

    float myssq = 0.f;

#pragma unroll
    for (int r = 0; r < 6; ++r) {
        const int sla = r % 3;          // row above (gh+r-1)
        const int slc = (r + 1) % 3;    // center    (gh+r)
        const int slb = (r + 2) % 3;    // below     (gh+r+1)
        LOADROW(gh + r + 1, slb);

        float o[6];
#pragma unroll
        for (int j = 0; j < 6; ++j) {
            const float a0 = (j == 0) ? lf[sla] : rbuf[sla][j - 1];
            const float b0 = (j == 0) ? lf[slc] : rbuf[slc][j - 1];
            const float c0 = (j == 0) ? lf[slb] : rbuf[slb][j - 1];
            o[j] = w00 * a0 + w01 * rbuf[sla][j] + w02 * rbuf[sla][j + 1]
                 + w10 * b0 + w11 * rbuf[slc][j] + w12 * rbuf[slc][j + 1]
                 + w20 * c0 + w21 * rbuf[slb][j] + w22 * rbuf[slb][j + 1];
        }

        unsigned int* dp = (unsigned int*)(dst + (long)(gh + r) * 192);
        dp[0] = (unsigned int)f2bf(o[0]) | ((unsigned int)f2bf(o[1]) << 16);
        dp[1] = (unsigned int)f2bf(o[2]) | ((unsigned int)f2bf(o[3]) << 16);
        dp[2] = (unsigned int)f2bf(o[4]) | ((unsigned int)f2bf(o[5]) << 16);

#pragma unroll
        for (int j = 0; j < 6; ++j) myssq += o[j] * o[j];
    }

    if (ch < 384) {
#pragma unroll
        for (int off = 32; off > 0; off >>= 1) myssq += __shfl_xor(myssq, off, 64);
        __shared__ float red[4];
        if (lane == 0) red[tid >> 6] = myssq;
        __syncthreads();
        if (tid == 0) atomicAdd(&ssq[b * 384 + ch], red[0] + red[1] + red[2] + red[3]);
    }
}

// ---------------------------------------------------------------------------
// Gram: gram[b,h,d,e] += sum_n q[d][n]*k[e][n]. 4 waves per block, each wave
// a 128-col sub-chunk of a 512-col chunk; LDS-reduce across waves, then one
// set of atomics per block.
// ---------------------------------------------------------------------------
__global__ __launch_bounds__(256) void gram_kernel(
    const unsigned short* __restrict__ dwb, float* __restrict__ gram)
{
    const int chunk = blockIdx.x;  // 0..71 (512-col chunks)
    const int bh = blockIdx.y;     // 0..7
    const int b = bh >> 2, h = bh & 3;
    const int tid = threadIdx.x;
    const int wave = tid >> 6;
    const int lane = tid & 63;
    const int row = lane & 15, qk = lane >> 4;
    const long n0 = (long)chunk * 512 + wave * 128;

    const unsigned short* qb = dwb + (long)(b * 576 + h * 48) * HW + n0;
    const unsigned short* kb = dwb + (long)(b * 576 + 192 + h * 48) * HW + n0;

    f32x4 acc[3][3];
#pragma unroll
    for (int f = 0; f < 3; ++f)
#pragma unroll
        for (int g = 0; g < 3; ++g) acc[f][g] = (f32x4){0.f, 0.f, 0.f, 0.f};

#pragma unroll
    for (int kk = 0; kk < 128; kk += 32) {
        const int col = kk + qk * 8;
        bf16x8 aq[3], bk[3];
#pragma unroll
        for (int f = 0; f < 3; ++f) aq[f] = *(const bf16x8*)(qb + (long)(f * 16 + row) * HW + col);
#pragma unroll
        for (int g = 0; g < 3; ++g) bk[g] = *(const bf16x8*)(kb + (long)(g * 16 + row) * HW + col);
#pragma unroll
        for (int f = 0; f < 3; ++f)
#pragma unroll
            for (int g = 0; g < 3; ++g)
                acc[f][g] = __builtin_amdgcn_mfma_f32_16x16x32_bf16(aq[f], bk[g], acc[f][g], 0, 0, 0);
    }

    // cross-wave LDS reduction (padded stride 37: conflict-light)
    __shared__ float sg[4][64][37];
#pragma unroll
    for (int f = 0; f < 3; ++f)
#pragma unroll
        for (int g = 0; g < 3; ++g)
#pragma unroll
            for (int i = 0; i < 4; ++i)
                sg[wave][lane][f * 12 + g * 4 + i] = acc[f][g][i];
    __syncthreads();

    const int rl = tid >> 2;
    const int i0 = (tid & 3) * 9;
    const int rrow = rl & 15, rqk = rl >> 4;
    float* gb = gram + bh * 2304;
#pragma unroll
    for (int j = 0; j < 9; ++j) {
        const int idx = i0 + j;
        const float v = sg[0][rl][idx] + sg[1][rl][idx] + sg[2][rl][idx] + sg[3][rl][idx];
        const int f = idx / 12, rem = idx - f * 12, g = rem >> 2, i = rem & 3;
        atomicAdd(&gb[(f * 16 + rqk * 4 + i) * 48 + g * 16 + rrow], v);
    }
}

// ---------------------------------------------------------------------------
// attn = softmax( gram / (|q_d||k_e|) * softplus(logT) + eps ) over e
// ---------------------------------------------------------------------------
__global__ __launch_bounds__(64) void attn_kernel(
    const float* __restrict__ gram, const float* __restrict__ ssq,
    const float* __restrict__ lt, float* __restrict__ attn)
{
    const int bh = blockIdx.x;
    const int b = bh >> 2, h = bh & 3;
    const int d = threadIdx.x;
    if (d >= 48) return;
    const float temp = log1pf(expf(lt[h])) + 1e-6f;
    const float invq = 1.f / fmaxf(sqrtf(ssq[b * 384 + h * 48 + d]), 1e-12f);
    float p[48];
    float mx = -1e30f;
#pragma unroll
    for (int e = 0; e < 48; ++e) {
        float invk = 1.f / fmaxf(sqrtf(ssq[b * 384 + 192 + h * 48 + e]), 1e-12f);
        float g = gram[bh * 2304 + d * 48 + e] * invq * invk * temp;
        p[e] = g;
        mx = fmaxf(mx, g);
    }
    float sum = 0.f;
#pragma unroll
    for (int e = 0; e < 48; ++e) { float x = expf(p[e] - mx); p[e] = x; sum += x; }
    const float inv = 1.f / sum;
#pragma unroll
    for (int e = 0; e < 48; ++e) attn[bh * 2304 + d * 48 + e] = p[e] * inv;
}

// ---------------------------------------------------------------------------
// M[b][o][h*48+e] = sum_d wproj[o][h*48+d] * attn[b][h][d][e]   (bf16 out)
// ---------------------------------------------------------------------------
__global__ __launch_bounds__(192) void mproj_kernel(
    const float* __restrict__ wproj, const float* __restrict__ attn,
    unsigned short* __restrict__ Mb)
{
    const int o = blockIdx.x;
    const int b = blockIdx.y;
    const int he = threadIdx.x;
    const int h = he / 48, e = he - h * 48;
    const float* ar = attn + ((b * 4 + h) * 48) * 48 + e;
    const float* wr = wproj + o * 192 + h * 48;
    float acc = 0.f;
#pragma unroll
    for (int d = 0; d < 48; ++d) acc += wr[d] * ar[d * 48];
    Mb[(long)(b * 192 + o) * 192 + he] = f2bf(acc);
}

__global__ void cvt_bf16_kernel(const float* __restrict__ in,
                                unsigned short* __restrict__ out, int n)
{
    int i = blockIdx.x * 256 + threadIdx.x;
    if (i < n) out[i] = f2bf(in[i]);
}

// X f32 -> bf16, 8 elems/thread, exact grid (no bounds check needed)
__global__ __launch_bounds__(256) void cvt_x_kernel(
    const float* __restrict__ in, unsigned short* __restrict__ out)
{
    const long i = ((long)blockIdx.x * 256 + threadIdx.x) * 8;
    float4 a = *(const float4*)(in + i);
    float4 b = *(const float4*)(in + i + 4);
    int4 st;
    unsigned short* u = (unsigned short*)&st;
    u[0] = f2bf(a.x); u[1] = f2bf(a.y); u[2] = f2bf(a.z); u[3] = f2bf(a.w);
    u[4] = f2bf(b.x); u[5] = f2bf(b.y); u[6] = f2bf(b.z); u[7] = f2bf(b.w);
    *(int4*)(out + i) = st;
}

// ---------------------------------------------------------------------------
extern "C" void kernel_launch(void* const* d_in, const int* in_sizes, int n_in,
                              void* d_out, int out_size, void* d_ws, size_t ws_size,
                              hipStream_t stream)
{
    const float* x      = (const float*)d_in[0];
    const float* w_qkv  = (const float*)d_in[1];
    const float* w_dw   = (const float*)d_in[2];
    const float* w_proj = (const float*)d_in[3];
    const float* lt     = (const float*)d_in[4];

    char* ws = (char*)d_ws;
    unsigned short* wqkv_b = (unsigned short*)(ws + 0);          // 221184 B
    float* gram            = (float*)(ws + 221184);              // 73728 B
    float* ssq             = (float*)(ws + 294912);              // 3072 B
    float* attn            = (float*)(ws + 297984);              // 73728 B
    unsigned short* Mb     = (unsigned short*)(ws + 371712);     // 147456 B
    unsigned short* qkvb   = (unsigned short*)(ws + 524288);     // 84934656 B
    unsigned short* dwb    = (unsigned short*)(ws + 524288 + 84934656ll);
    // xbf ALIASES dwb: xbf is only live before the qkv GEMM completes;
    // dwb is first written by dwconv (after it). Proven r5-r10.
    unsigned short* xbf    = dwb;                                // 28311552 B

    // zero the atomic accumulators (gram + ssq are adjacent)
    hipMemsetAsync(gram, 0, 73728 + 3072, stream);

    // w_qkv -> bf16
    cvt_bf16_kernel<<<dim3((110592 + 255) / 256), 256, 0, stream>>>(w_qkv, wqkv_b, 110592);

    // x -> bf16 (2*192*36864 = 14155776 elems, 8/thread -> 6912 blocks exact)
    cvt_x_kernel<<<dim3(6912), 256, 0, stream>>>(x, xbf);

    // qkv = w_qkv @ x  (M=576, K=192, N=HW per batch)
    // NT=3 (REVERT to r10-verified 46.3 us; NT=6's 2.25 blk/CU under-fill
    // measured 56.1 us): grid (576/3)*3 = 576, 1152 blocks = 4.5/CU.
    gemm_rpa<true, true, 3, 3><<<dim3(576, 2), 256, 0, stream>>>(
        wqkv_b, xbf, (void*)qkvb,
        0L, (long)192 * HW, (long)576 * HW);

    // depthwise 3x3 + sumsq(q,k)  (overwrites the xbf alias region)
    dwconv_kernel<<<dim3(4, 576, 2), 256, 0, stream>>>(qkvb, w_dw, dwb, ssq);

    // gram = q @ k^T per (b, head): 4-wave blocks, LDS-reduced
    gram_kernel<<<dim3(72, 8), 256, 0, stream>>>(dwb, gram);

    // softmax(normalized gram * temperature)
    attn_kernel<<<dim3(8), 64, 0, stream>>>(gram, ssq, lt, attn);

    // M = w_proj @ attn (per batch, per head), bf16
    mproj_kernel<<<dim3(192, 2), 192, 0, stream>>>(w_proj, attn, Mb);

    // out = M @ v  (M=192, K=192, N=HW per batch), fp32 out
    // NT=1 (was 2): 576 -> 1152 blocks = 4.5/CU fill, same law as qkv.
    gemm_rpa<false, true, 1, 1><<<dim3(576, 2), 256, 0, stream>>>(
        Mb, dwb + (long)384 * HW, d_out,
        (long)192 * 192, (long)576 * HW, (long)192 * HW);
}